// Round 3
// baseline (994.430 us; speedup 1.0000x reference)
//
#include <hip/hip_runtime.h>
#include <hip/hip_bf16.h>
#include <hip/hip_fp16.h>

// Problem dims (fixed)
#define S_LEN  4096
#define BATCH  8
#define HD     1024          // D == H
#define N3     3072          // 3H
#define MTOT   (S_LEN * BATCH)   // 32768 GEMM rows
#define KD     1024          // GEMM K
#define CHUNK  64
#define NCHUNK (S_LEN / CHUNK)   // 64
#define LDK    72            // LDS row stride: 64 + 8 pad

typedef __bf16 bf16x8 __attribute__((ext_vector_type(8)));
typedef float  f32x4  __attribute__((ext_vector_type(4)));

__device__ __forceinline__ float sigmoid_f(float x) {
    return 1.0f / (1.0f + __expf(-x));
}
__device__ __forceinline__ float tanh_f(float x) {
    return 1.0f - 2.0f / (__expf(2.0f * x) + 1.0f);
}

// ---------------------------------------------------------------------------
// fp32 -> bf16 elementwise convert (8 elems/thread, exact grid)
// ---------------------------------------------------------------------------
__global__ __launch_bounds__(256)
void cvt_f32_to_bf16(const float* __restrict__ in, __hip_bfloat16* __restrict__ out)
{
    const size_t i = ((size_t)blockIdx.x * 256 + threadIdx.x) * 8;
    const float4 a = *(const float4*)(in + i);
    const float4 b = *(const float4*)(in + i + 4);
    bf16x8 v;
    v[0] = (__bf16)a.x; v[1] = (__bf16)a.y; v[2] = (__bf16)a.z; v[3] = (__bf16)a.w;
    v[4] = (__bf16)b.x; v[5] = (__bf16)b.y; v[6] = (__bf16)b.z; v[7] = (__bf16)b.w;
    *(bf16x8*)((__bf16*)out + i) = v;
}

// ---------------------------------------------------------------------------
// W [K,N] fp32 -> Wt [N,K] bf16, 32x32 LDS tiles
// ---------------------------------------------------------------------------
__global__ __launch_bounds__(256)
void transpose_w(const float* __restrict__ W, __hip_bfloat16* __restrict__ Wt)
{
    __shared__ float tile[32][33];
    const int n0 = blockIdx.x * 32;
    const int k0 = blockIdx.y * 32;
    const int tx = threadIdx.x;      // 0..31
    const int ty = threadIdx.y;      // 0..7
    #pragma unroll
    for (int r = ty; r < 32; r += 8)
        tile[r][tx] = W[(size_t)(k0 + r) * N3 + n0 + tx];
    __syncthreads();
    #pragma unroll
    for (int r = ty; r < 32; r += 8)
        Wt[(size_t)(n0 + r) * KD + k0 + tx] = __float2bfloat16(tile[tx][r]);
}

// ---------------------------------------------------------------------------
// GEMM: G[m,n] = act( A[m,:] . Bt[n,:] + bias[n] ),  act = sigmoid for n>=H
// A: [MTOT,KD] bf16; Bt: [N3,KD] bf16; bias fp32; G: [MTOT,N3] fp16
// 128x128 tile, BK=64, 4 waves of 64x64, mfma_f32_16x16x32_bf16,
// register staging -> ds_write_b128 (padded LDS rows)
// ---------------------------------------------------------------------------
__global__ __launch_bounds__(256)
void gemm_gates(const __hip_bfloat16* __restrict__ A,
                const __hip_bfloat16* __restrict__ Bt,
                const float* __restrict__ bias,
                __half* __restrict__ G)
{
    __shared__ __hip_bfloat16 As[128 * LDK];
    __shared__ __hip_bfloat16 Bs[128 * LDK];

    const int tid  = threadIdx.x;
    const int wave = tid >> 6;
    const int lane = tid & 63;
    const int m0 = blockIdx.y * 128;
    const int n0 = blockIdx.x * 128;
    const int wm = (wave >> 1) * 64;
    const int wn = (wave & 1) * 64;

    const int srow = tid >> 3;        // 0..31
    const int scol = (tid & 7) * 8;   // 0..56

    f32x4 acc[4][4] = {};

    #pragma unroll 1
    for (int kt = 0; kt < KD; kt += 64) {
        bf16x8 ra[4], rb[4];
        #pragma unroll
        for (int it = 0; it < 4; ++it) {
            const int r = srow + it * 32;
            ra[it] = *(const bf16x8*)(A  + (size_t)(m0 + r) * KD + kt + scol);
            rb[it] = *(const bf16x8*)(Bt + (size_t)(n0 + r) * KD + kt + scol);
        }
        __syncthreads();
        #pragma unroll
        for (int it = 0; it < 4; ++it) {
            const int r = srow + it * 32;
            *(bf16x8*)(As + r * LDK + scol) = ra[it];
            *(bf16x8*)(Bs + r * LDK + scol) = rb[it];
        }
        __syncthreads();

        #pragma unroll
        for (int kk = 0; kk < 2; ++kk) {
            const int klocal = kk * 32 + (lane >> 4) * 8;   // k = quad*8 + j
            const int mrow = wm + (lane & 15);
            const int nrow = wn + (lane & 15);
            bf16x8 af[4], bfr[4];
            #pragma unroll
            for (int i = 0; i < 4; ++i)
                af[i] = *(const bf16x8*)(As + (mrow + i * 16) * LDK + klocal);
            #pragma unroll
            for (int t = 0; t < 4; ++t)
                bfr[t] = *(const bf16x8*)(Bs + (nrow + t * 16) * LDK + klocal);
            #pragma unroll
            for (int i = 0; i < 4; ++i)
                #pragma unroll
                for (int t = 0; t < 4; ++t)
                    acc[i][t] = __builtin_amdgcn_mfma_f32_16x16x32_bf16(
                        af[i], bfr[t], acc[i][t], 0, 0, 0);
        }
    }

    // D: row = (lane>>4)*4 + r, col = lane&15
    const int lrow = (lane >> 4) * 4;
    const int lcol = lane & 15;
    #pragma unroll
    for (int i = 0; i < 4; ++i) {
        #pragma unroll
        for (int t = 0; t < 4; ++t) {
            const int n = n0 + wn + t * 16 + lcol;
            const float bv = bias[n];
            const bool sig = (n >= HD);
            #pragma unroll
            for (int r = 0; r < 4; ++r) {
                const int m = m0 + wm + i * 16 + lrow + r;
                float v = acc[i][t][r] + bv;
                if (sig) v = sigmoid_f(v);
                G[(size_t)m * N3 + n] = __float2half(v);
            }
        }
    }
}

// ---------------------------------------------------------------------------
// Scan pass A: per-chunk affine composition. c_out = Aacc * c_in + Bacc
// ---------------------------------------------------------------------------
__global__ __launch_bounds__(256)
void scan_a(const __half* __restrict__ G,
            float* __restrict__ cA, float* __restrict__ cB)
{
    const int tid = threadIdx.x;
    const int h = (blockIdx.x & 3) * 256 + tid;
    const int b = (blockIdx.x >> 2) & 7;
    const int j = blockIdx.x >> 5;

    const size_t step = (size_t)BATCH * N3;
    const size_t base = ((size_t)(j * CHUNK) * BATCH + b) * N3;
    const __half* pu = G + base + h;
    const __half* pf = G + base + HD + h;

    float Aacc = 1.0f, Bacc = 0.0f;
    #pragma unroll 4
    for (int s = 0; s < CHUNK; ++s) {
        const float f = __half2float(*pf);
        const float u = __half2float(*pu);
        Bacc = f * Bacc + (1.0f - f) * u;
        Aacc *= f;
        pu += step; pf += step;
    }
    const int idx = (j * BATCH + b) * HD + h;
    cA[idx] = Aacc;
    cB[idx] = Bacc;
}

// ---------------------------------------------------------------------------
// Scan pass B: sequential prefix over chunks; emits chunk-start c and c_last
// ---------------------------------------------------------------------------
__global__ __launch_bounds__(256)
void scan_b(const float* __restrict__ cA, const float* __restrict__ cB,
            const float* __restrict__ h0,        // [B*H] slice for this layer
            float* __restrict__ cstart,          // [NCHUNK,B,H]
            float* __restrict__ c_out)           // [B*H] hidden slot (fp32)
{
    const int tid = blockIdx.x * 256 + threadIdx.x;  // 0..8191
    const int b = tid >> 10;
    const int h = tid & 1023;
    float c = h0[b * HD + h];
    #pragma unroll 8
    for (int j = 0; j < NCHUNK; ++j) {
        const int idx = (j * BATCH + b) * HD + h;
        cstart[idx] = c;
        c = cA[idx] * c + cB[idx];
    }
    c_out[b * HD + h] = c;
}

// ---------------------------------------------------------------------------
// Scan pass C: replay chunk; h = o*tanh(c) + (1-o)*x
// OUT_F32=false: write bf16 (layer-1 h1, may alias xin — read precedes write)
// OUT_F32=true : write fp32 (layer-2 final output)
// ---------------------------------------------------------------------------
template<bool OUT_F32>
__global__ __launch_bounds__(256)
void scan_c(const __half* __restrict__ G,
            const __hip_bfloat16* __restrict__ xin,
            const float* __restrict__ cstart,
            __hip_bfloat16* __restrict__ hout_bf,
            float* __restrict__ hout_f32)
{
    const int tid = threadIdx.x;
    const int h = (blockIdx.x & 3) * 256 + tid;
    const int b = (blockIdx.x >> 2) & 7;
    const int j = blockIdx.x >> 5;

    float c = cstart[(j * BATCH + b) * HD + h];

    const size_t mbase = (size_t)(j * CHUNK) * BATCH + b;
    const size_t stepg = (size_t)BATCH * N3;
    const size_t steph = (size_t)BATCH * HD;
    const __half* pu = G + mbase * N3 + h;
    const __half* pf = pu + HD;
    const __half* po = pu + 2 * HD;
    const __hip_bfloat16* px = xin + mbase * HD + h;
    __hip_bfloat16* pb = hout_bf ? hout_bf + mbase * HD + h : nullptr;
    float* pw = hout_f32 ? hout_f32 + mbase * HD + h : nullptr;

    #pragma unroll 4
    for (int s = 0; s < CHUNK; ++s) {
        const float f = __half2float(*pf);
        const float u = __half2float(*pu);
        const float o = __half2float(*po);
        const float x = __bfloat162float(*px);
        c = f * c + (1.0f - f) * u;
        const float hv = o * tanh_f(c) + (1.0f - o) * x;
        if (OUT_F32) { *pw = hv; pw += steph; }
        else         { *pb = __float2bfloat16(hv); pb += steph; }
        pu += stepg; pf += stepg; po += stepg; px += steph;
    }
}

// ---------------------------------------------------------------------------
extern "C" void kernel_launch(void* const* d_in, const int* in_sizes, int n_in,
                              void* d_out, int out_size, void* d_ws, size_t ws_size,
                              hipStream_t stream)
{
    const float* x  = (const float*)d_in[0];
    const float* h0 = (const float*)d_in[1];
    const float* W1 = (const float*)d_in[2];
    const float* b1 = (const float*)d_in[3];
    const float* W2 = (const float*)d_in[4];
    const float* b2 = (const float*)d_in[5];

    float* out     = (float*)d_out;
    float* h2_out  = out;                                  // [S,B,H] fp32
    float* hid_out = out + (size_t)S_LEN * BATCH * HD;     // [2,B,H] fp32

    // workspace carve-up (~268 MiB)
    char* ws = (char*)d_ws;
    auto carve = [&ws](size_t bytes) {
        char* p = ws;
        ws += (bytes + 255) & ~(size_t)255;
        return p;
    };
    const size_t G_BYTES   = (size_t)MTOT * N3 * 2;            // 192 MiB (fp16)
    const size_t XB_BYTES  = (size_t)MTOT * HD * 2;            // 64 MiB (bf16)
    const size_t WT_BYTES  = (size_t)N3 * KD * 2;              // 6 MiB (bf16)
    const size_t CAB_BYTES = (size_t)NCHUNK * BATCH * HD * 4;  // 2 MiB each

    __half* G           = (__half*)carve(G_BYTES);
    __hip_bfloat16* xb  = (__hip_bfloat16*)carve(XB_BYTES);  // x bf16; reused as h1
    __hip_bfloat16* Wt  = (__hip_bfloat16*)carve(WT_BYTES);
    float* cA           = (float*)carve(CAB_BYTES);
    float* cB           = (float*)carve(CAB_BYTES);
    float* cstart       = (float*)carve(CAB_BYTES);

    const dim3 tpb_t(32, 8);
    const dim3 grid_t(N3 / 32, KD / 32);
    const dim3 grid_g(N3 / 128, MTOT / 128);
    const int scan_blocks = NCHUNK * BATCH * 4;   // 2048
    const int cvt_blocks  = (int)(((size_t)MTOT * HD) / (256 * 8));  // 16384

    // ---- layer 1 ----
    cvt_f32_to_bf16<<<cvt_blocks, 256, 0, stream>>>(x, xb);
    transpose_w<<<grid_t, tpb_t, 0, stream>>>(W1, Wt);
    gemm_gates<<<grid_g, 256, 0, stream>>>(xb, Wt, b1, G);
    scan_a<<<scan_blocks, 256, 0, stream>>>(G, cA, cB);
    scan_b<<<32, 256, 0, stream>>>(cA, cB, h0, cstart, hid_out);
    // writes h1 over xb in place (per-element read precedes write)
    scan_c<false><<<scan_blocks, 256, 0, stream>>>(G, xb, cstart, xb, nullptr);

    // ---- layer 2 ----
    transpose_w<<<grid_t, tpb_t, 0, stream>>>(W2, Wt);
    gemm_gates<<<grid_g, 256, 0, stream>>>(xb, Wt, b2, G);
    scan_a<<<scan_blocks, 256, 0, stream>>>(G, cA, cB);
    scan_b<<<32, 256, 0, stream>>>(cA, cB, h0 + (size_t)BATCH * HD, cstart,
                                   hid_out + (size_t)BATCH * HD);
    scan_c<true><<<scan_blocks, 256, 0, stream>>>(G, xb, cstart, nullptr, h2_out);
}